// Round 9
// baseline (657.370 us; speedup 1.0000x reference)
//
#include <hip/hip_runtime.h>
#include <math.h>
#include <stdint.h>

#define D      512
#define K2T    1056      // [hi(512) | lo(512) | b2h,b2l,1,1 | zeros] padded to 33*32
#define HW     49
#define BM     128
#define BN     128
#define BK     32
#define NSWEEP 4
#define KSTEPS 33        // K2T / BK
#define TTOT   (NSWEEP * KSTEPS)

typedef __attribute__((ext_vector_type(8))) _Float16 f16x8;
typedef __attribute__((ext_vector_type(4))) float f32x4;
typedef __attribute__((address_space(3))) uint32_t lds_t;
typedef const __attribute__((address_space(1))) uint32_t glb_t;

// ---- GAP + fp16 hi/lo split, coalesced: block stages 256 rows (50KB) in LDS ----
__global__ __launch_bounds__(256) void gap_split_kernel(const float* __restrict__ x,
                                                        _Float16* __restrict__ emb2) {
    __shared__ float g[256 * HW];          // 50176 B
    const int tid = threadIdx.x;
    const float4* x4 = (const float4*)x + (size_t)blockIdx.x * (256 * HW / 4);
    float4* g4 = (float4*)g;
#pragma unroll
    for (int i = 0; i < 12; ++i) {         // 12*256 = 3072 of 3136 float4s
        g4[tid + i * 256] = x4[tid + i * 256];
    }
    if (tid < 64) g4[tid + 3072] = x4[tid + 3072];
    __syncthreads();
    const float* p = g + tid * HW;         // lane stride 49 (odd) -> conflict-free
    float s = 0.f;
#pragma unroll
    for (int j = 0; j < HW; ++j) s += p[j];
    s *= (1.f / 49.f);
    _Float16 hi = (_Float16)s;
    _Float16 lo = (_Float16)(s - (float)hi);
    int r = blockIdx.x * 256 + tid;
    int m = r >> 9, c = r & 511;
    emb2[(size_t)m * K2T + c]       = hi;
    emb2[(size_t)m * K2T + 512 + c] = lo;
}

// ---- per-row a2 + A-tail [1,1,a2h,a2l,0...]: one wave per emb row ----
__global__ void finishA_kernel(_Float16* __restrict__ emb2, int M) {
    int row = blockIdx.x * 4 + (threadIdx.x >> 6);
    if (row >= M) return;
    int lane = threadIdx.x & 63;
    _Float16* p = emb2 + (size_t)row * K2T;
    f16x8 h = *(const f16x8*)(p + lane * 8);
    f16x8 l = *(const f16x8*)(p + 512 + lane * 8);
    float s = 0.f;
#pragma unroll
    for (int i = 0; i < 8; ++i) { float v = (float)h[i] + (float)l[i]; s = fmaf(v, v, s); }
#pragma unroll
    for (int m2 = 32; m2; m2 >>= 1) s += __shfl_xor(s, m2, 64);
    if (lane == 0) {
        _Float16 a2h = (_Float16)s;
        _Float16 a2l = (_Float16)(s - (float)a2h);
        _Float16 one = (_Float16)1.f, z0 = (_Float16)0.f;
        f16x8 t0 = {one, one, a2h, a2l, z0, z0, z0, z0};
        f16x8 z  = {z0, z0, z0, z0, z0, z0, z0, z0};
        *(f16x8*)(p + 1024) = t0;
        *(f16x8*)(p + 1032) = z;
        *(f16x8*)(p + 1040) = z;
        *(f16x8*)(p + 1048) = z;
    }
}

// ---- db -> [-2b split | b2h,b2l,1,1 | 0] fused with sqnorm: one wave per row ----
__global__ void split_db_kernel(const float* __restrict__ db,
                                _Float16* __restrict__ db2, int N, int N2) {
    int row = blockIdx.x * 4 + (threadIdx.x >> 6);
    if (row >= N2) return;
    int lane = threadIdx.x & 63;
    _Float16* q = db2 + (size_t)row * K2T;
    _Float16 z0 = (_Float16)0.f;
    f16x8 z = {z0, z0, z0, z0, z0, z0, z0, z0};
    if (row < N) {
        const float* p = db + (size_t)row * D + lane * 8;
        float4 v0 = *(const float4*)p;
        float4 v1 = *(const float4*)(p + 4);
        float vv[8] = {v0.x, v0.y, v0.z, v0.w, v1.x, v1.y, v1.z, v1.w};
        f16x8 h, l;
        float s = 0.f;
#pragma unroll
        for (int i = 0; i < 8; ++i) {
            float v = vv[i];
            s = fmaf(v, v, s);
            float wv = -2.f * v;                 // fold the -2 into B
            _Float16 hh = (_Float16)wv;
            h[i] = hh;
            l[i] = (_Float16)(wv - (float)hh);
        }
        *(f16x8*)(q + lane * 8)       = h;
        *(f16x8*)(q + 512 + lane * 8) = l;
#pragma unroll
        for (int m2 = 32; m2; m2 >>= 1) s += __shfl_xor(s, m2, 64);
        if (lane == 0) {
            _Float16 b2h = (_Float16)s;
            _Float16 b2l = (_Float16)(s - (float)b2h);
            _Float16 one = (_Float16)1.f;
            f16x8 t0 = {b2h, b2l, one, one, z0, z0, z0, z0};
            *(f16x8*)(q + 1024) = t0;
            *(f16x8*)(q + 1032) = z;
            *(f16x8*)(q + 1040) = z;
            *(f16x8*)(q + 1048) = z;
        }
    } else {
        *(f16x8*)(q + lane * 8)       = z;
        *(f16x8*)(q + 512 + lane * 8) = z;
        if (lane < 4) *(f16x8*)(q + 1024 + lane * 8) = z;
    }
}

__global__ void init_keys_kernel(unsigned long long* __restrict__ keys, int M) {
    int b = blockIdx.x * blockDim.x + threadIdx.x;
    if (b < M) keys[b] = ~0ull;
}

// ---- fused MFMA GEMM (acc == d^2 directly) + min/argmin ----
// depth-2 counted-vmcnt pipeline, 3 LDS buffer sets, XCD-chunked swizzle,
// 16B-slot XOR swizzle (slot ^= (row>>1)&3) on BOTH stage-source and read (rule #21).
__global__ __launch_bounds__(256) void dist_kernel(
        const _Float16* __restrict__ A2, const _Float16* __restrict__ B2,
        unsigned long long* __restrict__ keys, int N, int nXcdChunk)
{
    __shared__ _Float16 lds[3 * 8192];   // 3 sets x (8KB A + 8KB B) = 48KB
    const int tid  = threadIdx.x;
    const int lane = tid & 63;
    const int w    = tid >> 6;
    const int wr   = w >> 1, wc = w & 1;
    const int l15  = lane & 15, lg = lane >> 4;

    // bijective XCD-chunked remap: consecutive blocks on one XCD share the B supertile
    const int bb   = blockIdx.x;
    const int swz  = (bb & 7) * nXcdChunk + (bb >> 3);
    const int mBase = (swz & 15) * BM;
    const long long nSuperBase = (long long)(swz >> 4) * (BN * NSWEEP);

    const int o0 = w * 1024 + lane * 16;   // byte slot in a 4KB stage chunk

    auto STAGE = [&](unsigned bufByte, int tt) {
        const int k0 = (tt % KSTEPS) * BK;
        const long long nB = nSuperBase + (long long)(tt / KSTEPS) * BN;
#pragma unroll
        for (int q = 0; q < 2; ++q) {
            const int o = o0 + q * 4096;
            const int row = o >> 6;
            const int slot = (o >> 4) & 3;
            const int cb = ((slot ^ ((row >> 1) & 3)) << 4);   // pre-swizzled source
            const char* ga = (const char*)A2 + ((size_t)(mBase + row) * K2T + k0) * 2 + cb;
            const char* gb = (const char*)B2 + ((size_t)(nB + row) * K2T + k0) * 2 + cb;
            char* la = (char*)lds + bufByte + q * 4096 + w * 1024;
            __builtin_amdgcn_global_load_lds((glb_t*)ga, (lds_t*)la, 16, 0, 0);
            __builtin_amdgcn_global_load_lds((glb_t*)gb, (lds_t*)(la + 8192), 16, 0, 0);
        }
    };

    unsigned long long key[4][4];
#pragma unroll
    for (int mF = 0; mF < 4; ++mF)
#pragma unroll
        for (int r = 0; r < 4; ++r) key[mF][r] = ~0ull;

    f32x4 acc[4][4];
#pragma unroll
    for (int mF = 0; mF < 4; ++mF)
#pragma unroll
        for (int nF = 0; nF < 4; ++nF) acc[mF][nF] = (f32x4){0.f, 0.f, 0.f, 0.f};

    STAGE(0, 0);
    STAGE(16384, 1);
    unsigned bufR = 0, bufN = 16384, bufP = 32768;

    // swizzled read slot: row&.. depends only on l15 (row = 16-mult + l15)
    const int sw = (lg ^ ((l15 >> 1) & 3)) * 8;   // f16-element offset of my 16B slot

    for (int t = 0; t < TTOT; ++t) {
        // tile t landed (mine); barrier makes it true for all waves. Never drain
        // to 0 mid-loop: tile t+1 stays in flight across the barrier.
        if (t < TTOT - 1) asm volatile("s_waitcnt vmcnt(4)" ::: "memory");
        else              asm volatile("s_waitcnt vmcnt(0)" ::: "memory");
        __builtin_amdgcn_s_barrier();

        const _Float16* As = (const _Float16*)((const char*)lds + bufR);
        const _Float16* Bs = As + 4096;
        f16x8 af[4], bf[4];
#pragma unroll
        for (int mF = 0; mF < 4; ++mF)
            af[mF] = *(const f16x8*)(As + (wr * 64 + mF * 16 + l15) * BK + sw);
#pragma unroll
        for (int nF = 0; nF < 4; ++nF)
            bf[nF] = *(const f16x8*)(Bs + (wc * 64 + nF * 16 + l15) * BK + sw);

        // prefetch tile t+2 into the set freed at the barrier above
        if (t + 2 < TTOT) STAGE(bufP, t + 2);

        __builtin_amdgcn_s_setprio(1);
#pragma unroll
        for (int mF = 0; mF < 4; ++mF)
#pragma unroll
            for (int nF = 0; nF < 4; ++nF)
                acc[mF][nF] = __builtin_amdgcn_mfma_f32_16x16x32_f16(
                    af[mF], bf[nF], acc[mF][nF], 0, 0, 0);
        __builtin_amdgcn_s_setprio(0);

        if (t % KSTEPS == KSTEPS - 1) {       // sweep complete: acc holds d^2
            const long long nBase = nSuperBase + (long long)(t / KSTEPS) * BN;
#pragma unroll
            for (int nF = 0; nF < 4; ++nF) {
                const long long g = nBase + wc * 64 + nF * 16 + l15;
                if (g < N) {
#pragma unroll
                    for (int mF = 0; mF < 4; ++mF)
#pragma unroll
                        for (int r = 0; r < 4; ++r) {
                            float d2 = fmaxf(acc[mF][nF][r], 0.f);
                            unsigned long long kk =
                                ((unsigned long long)__float_as_uint(d2) << 32) |
                                (unsigned long long)(unsigned)g;
                            key[mF][r] = key[mF][r] < kk ? key[mF][r] : kk;
                        }
                }
            }
#pragma unroll
            for (int mF = 0; mF < 4; ++mF)
#pragma unroll
                for (int nF = 0; nF < 4; ++nF) acc[mF][nF] = (f32x4){0.f, 0.f, 0.f, 0.f};
        }

        unsigned tmp = bufR; bufR = bufN; bufN = bufP; bufP = tmp;
    }

    // reduce across the 16 l15-lanes (same output rows, different cols)
#pragma unroll
    for (int mF = 0; mF < 4; ++mF)
#pragma unroll
        for (int r = 0; r < 4; ++r) {
            unsigned long long k = key[mF][r];
#pragma unroll
            for (int m2 = 1; m2 < 16; m2 <<= 1) {
                unsigned long long o = __shfl_xor(k, m2, 16);
                k = k < o ? k : o;
            }
            if (l15 == 0)
                atomicMin(&keys[mBase + wr * 64 + mF * 16 + lg * 4 + r], k);
        }
}

__global__ void finalize_kernel(const unsigned long long* __restrict__ keys,
                                float* __restrict__ out_dist, float* __restrict__ out_idx, int M) {
    int b = blockIdx.x * blockDim.x + threadIdx.x;
    if (b >= M) return;
    unsigned long long k = keys[b];
    float d2 = __uint_as_float((unsigned)(k >> 32));
    out_dist[b] = sqrtf(fmaxf(d2, 0.f));
    out_idx[b]  = (float)(unsigned)(k & 0xffffffffu);  // idx as float VALUE (<2^24 exact)
}

extern "C" void kernel_launch(void* const* d_in, const int* in_sizes, int n_in,
                              void* d_out, int out_size, void* d_ws, size_t ws_size,
                              hipStream_t stream) {
    const float* x  = (const float*)d_in[0];
    const float* db = (const float*)d_in[1];
    float* out = (float*)d_out;

    const int M  = in_sizes[0] / (D * HW);              // 2048
    const int N  = in_sizes[1] / D;                     // 50000
    const int nTiles  = (N + BN - 1) / BN;              // 391
    const int nSupers = (nTiles + NSWEEP - 1) / NSWEEP; // 98
    const int N2 = nSupers * NSWEEP * BN;               // 50176
    const int mTiles = M / BM;                          // 16
    const int nBlocks = nSupers * mTiles;               // 1568 (divisible by 8)
    const int nXcdChunk = nBlocks / 8;                  // 196

    char* ws = (char*)d_ws;
    _Float16* emb2 = (_Float16*)ws;                     // M  x K2T (~4.3 MB)
    _Float16* db2  = emb2 + (size_t)M * K2T;            // N2 x K2T (~106 MB)
    unsigned long long* keys =
        (unsigned long long*)(((uintptr_t)(db2 + (size_t)N2 * K2T) + 7) & ~(uintptr_t)7);

    const int rows = M * D;                             // 1048576 = 4096 * 256
    gap_split_kernel<<<rows / 256, 256, 0, stream>>>(x, emb2);
    finishA_kernel<<<(M + 3) / 4, 256, 0, stream>>>(emb2, M);
    split_db_kernel<<<(N2 + 3) / 4, 256, 0, stream>>>(db, db2, N, N2);
    init_keys_kernel<<<(M + 255) / 256, 256, 0, stream>>>(keys, M);

    dist_kernel<<<nBlocks, 256, 0, stream>>>(emb2, db2, keys, N, nXcdChunk);

    finalize_kernel<<<(M + 255) / 256, 256, 0, stream>>>(keys, out, out + M, M);
}

// Round 10
// 618.184 us; speedup vs baseline: 1.0634x; 1.0634x over previous
//
#include <hip/hip_runtime.h>
#include <math.h>
#include <stdint.h>

#define D      512
#define K2T    1088      // [hi(512) | lo(512) | b2h,b2l,1,1 | zeros] padded to 17*64
#define HW     49
#define BM     256
#define BN     256
#define KTILES 17        // K2T / 64

typedef __attribute__((ext_vector_type(8))) _Float16 f16x8;
typedef __attribute__((ext_vector_type(4))) float f32x4;
typedef __attribute__((address_space(3))) uint32_t lds_t;
typedef const __attribute__((address_space(1))) uint32_t glb_t;

// ---- GAP + fp16 hi/lo split, coalesced via LDS staging ----
__global__ __launch_bounds__(256) void gap_split_kernel(const float* __restrict__ x,
                                                        _Float16* __restrict__ emb2) {
    __shared__ float g[256 * HW];          // 50176 B
    const int tid = threadIdx.x;
    const float4* x4 = (const float4*)x + (size_t)blockIdx.x * (256 * HW / 4);
    float4* g4 = (float4*)g;
#pragma unroll
    for (int i = 0; i < 12; ++i) g4[tid + i * 256] = x4[tid + i * 256];
    if (tid < 64) g4[tid + 3072] = x4[tid + 3072];
    __syncthreads();
    const float* p = g + tid * HW;
    float s = 0.f;
#pragma unroll
    for (int j = 0; j < HW; ++j) s += p[j];
    s *= (1.f / 49.f);
    _Float16 hi = (_Float16)s;
    _Float16 lo = (_Float16)(s - (float)hi);
    int r = blockIdx.x * 256 + tid;
    int m = r >> 9, c = r & 511;
    emb2[(size_t)m * K2T + c]       = hi;
    emb2[(size_t)m * K2T + 512 + c] = lo;
}

// ---- per-row a2 + A-tail [1,1,a2h,a2l,0..0]: one wave per emb row ----
__global__ void finishA_kernel(_Float16* __restrict__ emb2, int M) {
    int row = blockIdx.x * 4 + (threadIdx.x >> 6);
    if (row >= M) return;
    int lane = threadIdx.x & 63;
    _Float16* p = emb2 + (size_t)row * K2T;
    f16x8 h = *(const f16x8*)(p + lane * 8);
    f16x8 l = *(const f16x8*)(p + 512 + lane * 8);
    float s = 0.f;
#pragma unroll
    for (int i = 0; i < 8; ++i) { float v = (float)h[i] + (float)l[i]; s = fmaf(v, v, s); }
#pragma unroll
    for (int m2 = 32; m2; m2 >>= 1) s += __shfl_xor(s, m2, 64);
    if (lane == 0) {
        _Float16 a2h = (_Float16)s;
        _Float16 a2l = (_Float16)(s - (float)a2h);
        _Float16 one = (_Float16)1.f, z0 = (_Float16)0.f;
        f16x8 t0 = {one, one, a2h, a2l, z0, z0, z0, z0};
        f16x8 z  = {z0, z0, z0, z0, z0, z0, z0, z0};
        *(f16x8*)(p + 1024) = t0;
#pragma unroll
        for (int q = 1; q < 8; ++q) *(f16x8*)(p + 1024 + q * 8) = z;
    }
}

// ---- db -> [-2b split | b2h,b2l,1,1 | 0] fused with sqnorm ----
__global__ void split_db_kernel(const float* __restrict__ db,
                                _Float16* __restrict__ db2, int N, int N2) {
    int row = blockIdx.x * 4 + (threadIdx.x >> 6);
    if (row >= N2) return;
    int lane = threadIdx.x & 63;
    _Float16* q = db2 + (size_t)row * K2T;
    _Float16 z0 = (_Float16)0.f;
    f16x8 z = {z0, z0, z0, z0, z0, z0, z0, z0};
    if (row < N) {
        const float* p = db + (size_t)row * D + lane * 8;
        float4 v0 = *(const float4*)p;
        float4 v1 = *(const float4*)(p + 4);
        float vv[8] = {v0.x, v0.y, v0.z, v0.w, v1.x, v1.y, v1.z, v1.w};
        f16x8 h, l;
        float s = 0.f;
#pragma unroll
        for (int i = 0; i < 8; ++i) {
            float v = vv[i];
            s = fmaf(v, v, s);
            float wv = -2.f * v;
            _Float16 hh = (_Float16)wv;
            h[i] = hh;
            l[i] = (_Float16)(wv - (float)hh);
        }
        *(f16x8*)(q + lane * 8)       = h;
        *(f16x8*)(q + 512 + lane * 8) = l;
#pragma unroll
        for (int m2 = 32; m2; m2 >>= 1) s += __shfl_xor(s, m2, 64);
        if (lane == 0) {
            _Float16 b2h = (_Float16)s;
            _Float16 b2l = (_Float16)(s - (float)b2h);
            _Float16 one = (_Float16)1.f;
            f16x8 t0 = {b2h, b2l, one, one, z0, z0, z0, z0};
            *(f16x8*)(q + 1024) = t0;
#pragma unroll
            for (int q2 = 1; q2 < 8; ++q2) *(f16x8*)(q + 1024 + q2 * 8) = z;
        }
    } else {
        *(f16x8*)(q + lane * 8)       = z;
        *(f16x8*)(q + 512 + lane * 8) = z;
        if (lane < 8) *(f16x8*)(q + 1024 + lane * 8) = z;
    }
}

__global__ void init_keys_kernel(unsigned long long* __restrict__ keys, int M) {
    int b = blockIdx.x * blockDim.x + threadIdx.x;
    if (b < M) keys[b] = ~0ull;
}

// ---- 256x256-tile, BK=64, 8-wave, 4-phase-per-K-tile pipelined GEMM (acc == d^2) ----
// LDS: 2 slots x (A 32KB + B 32KB) = 128 KiB. Stage schedule: A(t+1)@ph0,ph1;
// B(t+2)@ph1,ph2 -> exactly 4 loads in flight at the ph0 wait => vmcnt(4).
// 16B-slot swizzle slot^=(row&7) on BOTH stage-source and ds_read (involution).
__global__ __launch_bounds__(512, 2) void dist_kernel(
        const _Float16* __restrict__ A2, const _Float16* __restrict__ B2,
        unsigned long long* __restrict__ keys, int N, int nXcdChunk)
{
    __shared__ f16x8 ldsv[8192];           // 128 KiB
    char* ldsb = (char*)ldsv;
    const int tid  = threadIdx.x;
    const int lane = tid & 63;
    const int w    = tid >> 6;             // 0..7
    const int wr   = w >> 2, wc = w & 3;   // 2 x 4 wave grid; wave tile 128x64
    const int l15  = lane & 15, lg = lane >> 4;

    const int bb   = blockIdx.x;
    const int swzb = (bb & 7) * nXcdChunk + (bb >> 3);   // XCD-chunked, bijective
    const long long mBase = (long long)(swzb & 7) * BM;  // M fastest -> B-tile reuse in L2
    const long long nBase = (long long)(swzb >> 3) * BN;

    auto STAGE_A = [&](int s2, int h, int tile) {
#pragma unroll
        for (int pass = 0; pass < 2; ++pass) {
            const int o  = pass * 8192 + tid * 16;
            const int rl = o >> 7;
            const int sl = (o >> 4) & 7;
            const int r  = h * 128 + rl;
            const _Float16* g = A2 + (size_t)(mBase + r) * K2T + tile * 64 + ((sl ^ (r & 7)) << 3);
            char* lp = ldsb + s2 * 65536 + h * 16384 + pass * 8192 + w * 1024;
            __builtin_amdgcn_global_load_lds((glb_t*)g, (lds_t*)lp, 16, 0, 0);
        }
    };
    auto STAGE_B = [&](int s2, int h, int tile) {
#pragma unroll
        for (int pass = 0; pass < 2; ++pass) {
            const int o  = pass * 8192 + tid * 16;
            const int rl = o >> 7;
            const int sl = (o >> 4) & 7;
            const int r  = h * 128 + rl;
            const _Float16* g = B2 + (size_t)(nBase + r) * K2T + tile * 64 + ((sl ^ (r & 7)) << 3);
            char* lp = ldsb + s2 * 65536 + 32768 + h * 16384 + pass * 8192 + w * 1024;
            __builtin_amdgcn_global_load_lds((glb_t*)g, (lds_t*)lp, 16, 0, 0);
        }
    };

    f32x4 acc[8][4];
#pragma unroll
    for (int mF = 0; mF < 8; ++mF)
#pragma unroll
        for (int nF = 0; nF < 4; ++nF) acc[mF][nF] = (f32x4){0.f, 0.f, 0.f, 0.f};
    f16x8 bf[4][2], af[2][2];

    // prologue: tile0 (A+B) + tile1 (B); A(1) staged during iter 0
    STAGE_A(0, 0, 0); STAGE_A(0, 1, 0);
    STAGE_B(0, 0, 0); STAGE_B(0, 1, 0);
    STAGE_B(1, 0, 1); STAGE_B(1, 1, 1);

    for (int t = 0; t < KTILES; ++t) {
        const int s  = t & 1;
        const int sA = s * 65536;
        const int sB = sA + 32768;

        // ======== phase 0: B-frags + A-frags m0,1 | stage A-low(t+1) ========
        if (t < KTILES - 1) asm volatile("s_waitcnt vmcnt(4)" ::: "memory");
        else                asm volatile("s_waitcnt vmcnt(0)" ::: "memory");
        __builtin_amdgcn_s_barrier();      // all waves' tile-t loads landed
#pragma unroll
        for (int nF = 0; nF < 4; ++nF)
#pragma unroll
            for (int kk = 0; kk < 2; ++kk) {
                const int r = wc * 64 + nF * 16 + l15;
                bf[nF][kk] = *(const f16x8*)(ldsb + sB + r * 128 + (((kk << 2) | lg) ^ (r & 7)) * 16);
            }
#pragma unroll
        for (int j = 0; j < 2; ++j)
#pragma unroll
            for (int kk = 0; kk < 2; ++kk) {
                const int r = wr * 128 + (0 + j) * 16 + l15;
                af[j][kk] = *(const f16x8*)(ldsb + sA + r * 128 + (((kk << 2) | lg) ^ (r & 7)) * 16);
            }
        if (t + 1 < KTILES) STAGE_A(s ^ 1, 0, t + 1);
        __builtin_amdgcn_s_barrier();
        asm volatile("s_waitcnt lgkmcnt(0)" ::: "memory");
        __builtin_amdgcn_s_setprio(1);
#pragma unroll
        for (int j = 0; j < 2; ++j)
#pragma unroll
            for (int nF = 0; nF < 4; ++nF)
#pragma unroll
                for (int kk = 0; kk < 2; ++kk)
                    acc[0 + j][nF] = __builtin_amdgcn_mfma_f32_16x16x32_f16(af[j][kk], bf[nF][kk], acc[0 + j][nF], 0, 0, 0);
        __builtin_amdgcn_s_setprio(0);
        __builtin_amdgcn_s_barrier();

        // ======== phase 1: A-frags m2,3 | stage A-high(t+1), B-low(t+2) ========
#pragma unroll
        for (int j = 0; j < 2; ++j)
#pragma unroll
            for (int kk = 0; kk < 2; ++kk) {
                const int r = wr * 128 + (2 + j) * 16 + l15;
                af[j][kk] = *(const f16x8*)(ldsb + sA + r * 128 + (((kk << 2) | lg) ^ (r & 7)) * 16);
            }
        if (t + 1 < KTILES) STAGE_A(s ^ 1, 1, t + 1);
        if (t + 2 < KTILES) STAGE_B(s, 0, t + 2);
        __builtin_amdgcn_s_barrier();
        asm volatile("s_waitcnt lgkmcnt(0)" ::: "memory");
        __builtin_amdgcn_s_setprio(1);
#pragma unroll
        for (int j = 0; j < 2; ++j)
#pragma unroll
            for (int nF = 0; nF < 4; ++nF)
#pragma unroll
                for (int kk = 0; kk < 2; ++kk)
                    acc[2 + j][nF] = __builtin_amdgcn_mfma_f32_16x16x32_f16(af[j][kk], bf[nF][kk], acc[2 + j][nF], 0, 0, 0);
        __builtin_amdgcn_s_setprio(0);
        __builtin_amdgcn_s_barrier();

        // ======== phase 2: A-frags m4,5 | stage B-high(t+2) ========
#pragma unroll
        for (int j = 0; j < 2; ++j)
#pragma unroll
            for (int kk = 0; kk < 2; ++kk) {
                const int r = wr * 128 + (4 + j) * 16 + l15;
                af[j][kk] = *(const f16x8*)(ldsb + sA + r * 128 + (((kk << 2) | lg) ^ (r & 7)) * 16);
            }
        if (t + 2 < KTILES) STAGE_B(s, 1, t + 2);
        __builtin_amdgcn_s_barrier();
        asm volatile("s_waitcnt lgkmcnt(0)" ::: "memory");
        __builtin_amdgcn_s_setprio(1);
#pragma unroll
        for (int j = 0; j < 2; ++j)
#pragma unroll
            for (int nF = 0; nF < 4; ++nF)
#pragma unroll
                for (int kk = 0; kk < 2; ++kk)
                    acc[4 + j][nF] = __builtin_amdgcn_mfma_f32_16x16x32_f16(af[j][kk], bf[nF][kk], acc[4 + j][nF], 0, 0, 0);
        __builtin_amdgcn_s_setprio(0);
        __builtin_amdgcn_s_barrier();

        // ======== phase 3: A-frags m6,7 (no stage; trailing barrier folded into next ph0) ========
#pragma unroll
        for (int j = 0; j < 2; ++j)
#pragma unroll
            for (int kk = 0; kk < 2; ++kk) {
                const int r = wr * 128 + (6 + j) * 16 + l15;
                af[j][kk] = *(const f16x8*)(ldsb + sA + r * 128 + (((kk << 2) | lg) ^ (r & 7)) * 16);
            }
        __builtin_amdgcn_s_barrier();      // all waves' reads of slot s done
        asm volatile("s_waitcnt lgkmcnt(0)" ::: "memory");
        __builtin_amdgcn_s_setprio(1);
#pragma unroll
        for (int j = 0; j < 2; ++j)
#pragma unroll
            for (int nF = 0; nF < 4; ++nF)
#pragma unroll
                for (int kk = 0; kk < 2; ++kk)
                    acc[6 + j][nF] = __builtin_amdgcn_mfma_f32_16x16x32_f16(af[j][kk], bf[nF][kk], acc[6 + j][nF], 0, 0, 0);
        __builtin_amdgcn_s_setprio(0);
    }

    // ---- epilogue: pack keys, 16-lane reduce, cross-wave LDS reduce, 1 atomic/row ----
    unsigned long long* ldsK = (unsigned long long*)ldsv;   // safe: all tile reads done (ph3 barrier)
#pragma unroll
    for (int mF = 0; mF < 8; ++mF)
#pragma unroll
        for (int r = 0; r < 4; ++r) {
            unsigned long long k = ~0ull;
#pragma unroll
            for (int nF = 0; nF < 4; ++nF) {
                const long long g = nBase + wc * 64 + nF * 16 + l15;
                if (g < N) {
                    float d2 = fmaxf(acc[mF][nF][r], 0.f);
                    unsigned long long kk2 =
                        ((unsigned long long)__float_as_uint(d2) << 32) | (unsigned long long)(unsigned)g;
                    k = k < kk2 ? k : kk2;
                }
            }
#pragma unroll
            for (int m2 = 1; m2 < 16; m2 <<= 1) {
                unsigned long long o = __shfl_xor(k, m2, 16);
                k = k < o ? k : o;
            }
            if (l15 == 0) ldsK[(wr * 128 + mF * 16 + lg * 4 + r) * 4 + wc] = k;
        }
    __syncthreads();
    if (tid < 256) {
        unsigned long long k = ldsK[tid * 4 + 0];
#pragma unroll
        for (int q = 1; q < 4; ++q) {
            unsigned long long o = ldsK[tid * 4 + q];
            k = k < o ? k : o;
        }
        atomicMin(&keys[mBase + tid], k);
    }
}

__global__ void finalize_kernel(const unsigned long long* __restrict__ keys,
                                float* __restrict__ out_dist, float* __restrict__ out_idx, int M) {
    int b = blockIdx.x * blockDim.x + threadIdx.x;
    if (b >= M) return;
    unsigned long long k = keys[b];
    float d2 = __uint_as_float((unsigned)(k >> 32));
    out_dist[b] = sqrtf(fmaxf(d2, 0.f));
    out_idx[b]  = (float)(unsigned)(k & 0xffffffffu);  // idx as float VALUE (<2^24 exact)
}

extern "C" void kernel_launch(void* const* d_in, const int* in_sizes, int n_in,
                              void* d_out, int out_size, void* d_ws, size_t ws_size,
                              hipStream_t stream) {
    const float* x  = (const float*)d_in[0];
    const float* db = (const float*)d_in[1];
    float* out = (float*)d_out;

    const int M  = in_sizes[0] / (D * HW);              // 2048
    const int N  = in_sizes[1] / D;                     // 50000
    const int nTiles = (N + BN - 1) / BN;               // 196
    const int N2 = nTiles * BN;                         // 50176
    const int mTiles = M / BM;                          // 8
    const int nBlocks = mTiles * nTiles;                // 1568 (divisible by 8)
    const int nXcdChunk = nBlocks / 8;                  // 196

    char* ws = (char*)d_ws;
    _Float16* emb2 = (_Float16*)ws;                     // M  x K2T (~4.5 MB)
    _Float16* db2  = emb2 + (size_t)M * K2T;            // N2 x K2T (~109 MB)
    unsigned long long* keys =
        (unsigned long long*)(((uintptr_t)(db2 + (size_t)N2 * K2T) + 7) & ~(uintptr_t)7);

    const int rows = M * D;                             // 1048576 = 4096 * 256
    gap_split_kernel<<<rows / 256, 256, 0, stream>>>(x, emb2);
    finishA_kernel<<<(M + 3) / 4, 256, 0, stream>>>(emb2, M);
    split_db_kernel<<<(N2 + 3) / 4, 256, 0, stream>>>(db, db2, N, N2);
    init_keys_kernel<<<(M + 255) / 256, 256, 0, stream>>>(keys, M);

    dist_kernel<<<nBlocks, 512, 0, stream>>>(emb2, db2, keys, N, nXcdChunk);

    finalize_kernel<<<(M + 255) / 256, 256, 0, stream>>>(keys, out, out + M, M);
}